// Round 11
// baseline (130.366 us; speedup 1.0000x reference)
//
#include <hip/hip_runtime.h>
#include <math.h>

// ---------------- problem constants ----------------
#define NB        512
#define ND        32
#define NCOND     30
#define NS        21                  // NB_STEPS+1 quadrature nodes
#define NBD       (NB*ND)             // 16384
#define NROWS     (NBD*NS)            // 344064 MLP evaluations
#define MBLK      128                 // rows per block
#define NBLOCKS   (NROWS/MBLK)        // 2688

// packed-weight element counts (ushort)
#define W0P_ELEMS (1*16*64*8)         // 8192
#define W1P_ELEMS (8*16*64*8)         // 65536
#define W3P_ELEMS (8*64*8)            // 4096  (zero-padded W3 as A-fragments)
#define WP_TOTAL  (W0P_ELEMS + 2*W1P_ELEMS + W3P_ELEMS)  // 143360

typedef __bf16 bf8 __attribute__((ext_vector_type(8)));
typedef float  fx4 __attribute__((ext_vector_type(4)));
typedef unsigned short us8 __attribute__((ext_vector_type(8)));

__device__ __forceinline__ unsigned short f2bf(float f) {
  unsigned int u = __float_as_uint(f);
  u += 0x7FFFu + ((u >> 16) & 1u);        // round-to-nearest-even
  return (unsigned short)(u >> 16);
}

// ---------------- kernel 1: pack weights to bf16 MFMA fragment order ----------
__global__ void prep_pack(const float* __restrict__ W0,
                          const float* __restrict__ W1,
                          const float* __restrict__ W2,
                          const float* __restrict__ W3,
                          unsigned short* __restrict__ wp) {
  int t = blockIdx.x * blockDim.x + threadIdx.x;   // one thread = one 8-elem frag
  if (t >= WP_TOTAL / 8) return;
  int base = t * 8;
  us8 out;
  if (base >= W0P_ELEMS + 2 * W1P_ELEMS) {         // W3 region
    int rem  = base - (W0P_ELEMS + 2 * W1P_ELEMS);
    int lane = (rem >> 3) & 63;
    int ktl  = rem >> 9;
    int k0   = ktl * 32 + (lane >> 4) * 8;
#pragma unroll
    for (int i = 0; i < 8; ++i)
      out[i] = ((lane & 15) == 0) ? f2bf(W3[k0 + i]) : (unsigned short)0;
  } else {
    const float* W; int rem, K;
    if (base < W0P_ELEMS)                  { W = W0; rem = base;                 K = 31;  }
    else if (base < W0P_ELEMS + W1P_ELEMS) { W = W1; rem = base - W0P_ELEMS;     K = 256; }
    else                                   { W = W2; rem = base - W0P_ELEMS - W1P_ELEMS; K = 256; }
    int lane = (rem >> 3) & 63;
    int ct   = (rem >> 9) & 15;
    int ktl  =  rem >> 13;
    int j  = ct * 16 + (lane & 15);
    int k0 = ktl * 32 + (lane >> 4) * 8;
#pragma unroll
    for (int i = 0; i < 8; ++i) {
      int k = k0 + i;
      out[i] = (k < K) ? f2bf(W[k * 256 + j]) : (unsigned short)0;
    }
  }
  *reinterpret_cast<us8*>(wp + base) = out;
}

// ---------------- fused MLP kernel ----------------
// 4 waves/block (256 thr), block = 128 rows. Wave wv = neuron group cgrp=wv
// (64 neurons) x ALL 128 rows (8 row-tiles, acc[8][4] = 128 VGPR). Doubles
// per-wave MFMA per K-step to 32 (620 cyc) so 2 waves/SIMD fills the matrix
// pipe, and halves weight-L2 traffic vs R10 (each fragment serves 128 rows).
// launch_bounds(256,1): empirical cap = 256/arg2 (R4-R10) -> 256, spill-free
// at ~220 VGPR; HW self-limits at 2 waves/SIMD, 2 blocks/CU (LDS 64KB).
// In-place 64KB act buffer (input overlays first 8KB) + depth-2 weight
// pipeline + setprio unchanged from the verified R10 kernel.

#define ACC_ZERO                                                                 \
  _Pragma("unroll")                                                              \
  for (int rt = 0; rt < 8; ++rt)                                                 \
    _Pragma("unroll")                                                            \
    for (int ct = 0; ct < 4; ++ct) acc[rt][ct] = fx4{0.f, 0.f, 0.f, 0.f};

#define LOADW4(S0,S1,S2,S3, WB, KT)                                              \
  S0 = *reinterpret_cast<const bf8*>((WB) + (((KT) * 16 + cgrp * 4 + 0) * 64 + lane) * 8); \
  S1 = *reinterpret_cast<const bf8*>((WB) + (((KT) * 16 + cgrp * 4 + 1) * 64 + lane) * 8); \
  S2 = *reinterpret_cast<const bf8*>((WB) + (((KT) * 16 + cgrp * 4 + 2) * 64 + lane) * 8); \
  S3 = *reinterpret_cast<const bf8*>((WB) + (((KT) * 16 + cgrp * 4 + 3) * 64 + lane) * 8);

#define KROWS(RT, A_, W0_,W1_,W2_,W3_)                                           \
    acc[RT][0] = __builtin_amdgcn_mfma_f32_16x16x32_bf16(W0_, A_, acc[RT][0], 0, 0, 0); \
    acc[RT][1] = __builtin_amdgcn_mfma_f32_16x16x32_bf16(W1_, A_, acc[RT][1], 0, 0, 0); \
    acc[RT][2] = __builtin_amdgcn_mfma_f32_16x16x32_bf16(W2_, A_, acc[RT][2], 0, 0, 0); \
    acc[RT][3] = __builtin_amdgcn_mfma_f32_16x16x32_bf16(W3_, A_, acc[RT][3], 0, 0, 0);

#define AOFF(M, KT) (((unsigned)((M) * 512 + (KT) * 64 + khalf * 16)) ^ ((unsigned)(((M) & 15) << 4)))

#define KSTEP(W0_,W1_,W2_,W3_, KT)                                               \
  {                                                                              \
    bf8 a0 = *reinterpret_cast<const bf8*>(ldsAct + AOFF(  0 + colb, KT));       \
    bf8 a1 = *reinterpret_cast<const bf8*>(ldsAct + AOFF( 16 + colb, KT));       \
    bf8 a2 = *reinterpret_cast<const bf8*>(ldsAct + AOFF( 32 + colb, KT));       \
    bf8 a3 = *reinterpret_cast<const bf8*>(ldsAct + AOFF( 48 + colb, KT));       \
    bf8 a4 = *reinterpret_cast<const bf8*>(ldsAct + AOFF( 64 + colb, KT));       \
    bf8 a5 = *reinterpret_cast<const bf8*>(ldsAct + AOFF( 80 + colb, KT));       \
    bf8 a6 = *reinterpret_cast<const bf8*>(ldsAct + AOFF( 96 + colb, KT));       \
    bf8 a7 = *reinterpret_cast<const bf8*>(ldsAct + AOFF(112 + colb, KT));       \
    __builtin_amdgcn_s_setprio(1);                                               \
    KROWS(0, a0, W0_,W1_,W2_,W3_)                                                \
    KROWS(1, a1, W0_,W1_,W2_,W3_)                                                \
    KROWS(2, a2, W0_,W1_,W2_,W3_)                                                \
    KROWS(3, a3, W0_,W1_,W2_,W3_)                                                \
    KROWS(4, a4, W0_,W1_,W2_,W3_)                                                \
    KROWS(5, a5, W0_,W1_,W2_,W3_)                                                \
    KROWS(6, a6, W0_,W1_,W2_,W3_)                                                \
    KROWS(7, a7, W0_,W1_,W2_,W3_)                                                \
    __builtin_amdgcn_s_setprio(0);                                               \
  }

// K-steps 0..7, consuming alternating slots, prefetching kt+2 (then next layer)
#define DENSE_PIPE(WB, NWB)                                                      \
  KSTEP(wa0,wa1,wa2,wa3, 0) LOADW4(wa0,wa1,wa2,wa3, WB, 2)                       \
  KSTEP(wb0,wb1,wb2,wb3, 1) LOADW4(wb0,wb1,wb2,wb3, WB, 3)                       \
  KSTEP(wa0,wa1,wa2,wa3, 2) LOADW4(wa0,wa1,wa2,wa3, WB, 4)                       \
  KSTEP(wb0,wb1,wb2,wb3, 3) LOADW4(wb0,wb1,wb2,wb3, WB, 5)                       \
  KSTEP(wa0,wa1,wa2,wa3, 4) LOADW4(wa0,wa1,wa2,wa3, WB, 6)                       \
  KSTEP(wb0,wb1,wb2,wb3, 5) LOADW4(wb0,wb1,wb2,wb3, WB, 7)                       \
  KSTEP(wa0,wa1,wa2,wa3, 6) LOADW4(wa0,wa1,wa2,wa3, NWB, 0)                      \
  KSTEP(wb0,wb1,wb2,wb3, 7) LOADW4(wb0,wb1,wb2,wb3, NWB, 1)

#define DENSE_LAST(WB)                                                           \
  KSTEP(wa0,wa1,wa2,wa3, 0) LOADW4(wa0,wa1,wa2,wa3, WB, 2)                       \
  KSTEP(wb0,wb1,wb2,wb3, 1) LOADW4(wb0,wb1,wb2,wb3, WB, 3)                       \
  KSTEP(wa0,wa1,wa2,wa3, 2) LOADW4(wa0,wa1,wa2,wa3, WB, 4)                       \
  KSTEP(wb0,wb1,wb2,wb3, 3) LOADW4(wb0,wb1,wb2,wb3, WB, 5)                       \
  KSTEP(wa0,wa1,wa2,wa3, 4) LOADW4(wa0,wa1,wa2,wa3, WB, 6)                       \
  KSTEP(wb0,wb1,wb2,wb3, 5) LOADW4(wb0,wb1,wb2,wb3, WB, 7)                       \
  KSTEP(wa0,wa1,wa2,wa3, 6)                                                      \
  KSTEP(wb0,wb1,wb2,wb3, 7)

// bias + ReLU + bf16-pack + ds_write_b64 store of acc into ldsAct
#define ACT_STORE(BIAS)                                                          \
  {                                                                              \
    float4 bv0 = *reinterpret_cast<const float4*>((BIAS) + (cgrp * 4 + 0) * 16 + khalf * 4); \
    float4 bv1 = *reinterpret_cast<const float4*>((BIAS) + (cgrp * 4 + 1) * 16 + khalf * 4); \
    float4 bv2 = *reinterpret_cast<const float4*>((BIAS) + (cgrp * 4 + 2) * 16 + khalf * 4); \
    float4 bv3 = *reinterpret_cast<const float4*>((BIAS) + (cgrp * 4 + 3) * 16 + khalf * 4); \
    _Pragma("unroll")                                                            \
    for (int rt = 0; rt < 8; ++rt) {                                             \
      int m = rt * 16 + colb;                                                    \
      unsigned int sbase = (unsigned int)(m * 512);                              \
      unsigned int swz   = (unsigned int)((m & 15) << 4);                        \
      _Pragma("unroll")                                                          \
      for (int ct = 0; ct < 4; ++ct) {                                           \
        float4 bv = (ct == 0) ? bv0 : (ct == 1) ? bv1 : (ct == 2) ? bv2 : bv3;   \
        int n0 = (cgrp * 4 + ct) * 16 + khalf * 4;                               \
        float v0 = fmaxf(acc[rt][ct][0] + bv.x, 0.f);                            \
        float v1 = fmaxf(acc[rt][ct][1] + bv.y, 0.f);                            \
        float v2 = fmaxf(acc[rt][ct][2] + bv.z, 0.f);                            \
        float v3 = fmaxf(acc[rt][ct][3] + bv.w, 0.f);                            \
        unsigned int p0, p1;                                                     \
        asm("v_cvt_pk_bf16_f32 %0, %1, %2" : "=v"(p0) : "v"(v0), "v"(v1));       \
        asm("v_cvt_pk_bf16_f32 %0, %1, %2" : "=v"(p1) : "v"(v2), "v"(v3));       \
        uint2 pk; pk.x = p0; pk.y = p1;                                          \
        *reinterpret_cast<uint2*>(ldsAct + ((sbase + (unsigned int)(n0 * 2)) ^ swz)) = pk; \
      }                                                                          \
    }                                                                            \
  }

__global__ __launch_bounds__(256, 1)
void mlp_kernel(const float* __restrict__ x, const float* __restrict__ h,
                const float* __restrict__ b0, const float* __restrict__ b1,
                const float* __restrict__ b2, const float* __restrict__ b3,
                const unsigned short* __restrict__ wp,
                float* __restrict__ fbuf) {
  __shared__ __align__(16) unsigned char ldsAct[128 * 512];  // 64 KiB TOTAL
  unsigned char* ldsIn = ldsAct;       // layer-0 input overlays first 8 KB

  int tid  = threadIdx.x;
  int wv   = tid >> 6;
  int lane = tid & 63;
  int cgrp = wv;                 // 0..3 : 64-neuron group; wave owns all 128 rows
  int colb  = lane & 15;
  int khalf = lane >> 4;
  int R0 = blockIdx.x * MBLK;

  const unsigned short* wb1p = wp + W0P_ELEMS;
  const unsigned short* wb2p = wp + W0P_ELEMS + W1P_ELEMS;
  const unsigned short* w3p  = wp + W0P_ELEMS + 2 * W1P_ELEMS;

  bf8 wa0, wa1, wa2, wa3, wb0, wb1, wb2, wb3;
  // layer-0 weights (single K-step) into slot A, issued before input staging
  LOADW4(wa0, wa1, wa2, wa3, wp, 0);

  // ---- stage layer-0 input [128 rows][32 bf16] into ldsIn (= ldsAct[0:8K]) ----
#pragma unroll
  for (int it = 0; it < 2; ++it) {
    int idx = tid + it * 256;
    int r = idx >> 2;                   // 0..127
    int q = idx & 3;                    // 8-col chunk
    int gr = R0 + r;
    unsigned int bd = (unsigned int)gr / NS;
    int s = gr - (int)bd * NS;
    float xv = x[bd];
    float node = xv * (cosf((float)s * 0.15707963267948966f) + 1.0f) * 0.5f;
    const float* hrow = h + bd * NCOND;
    us8 au;
#pragma unroll
    for (int i = 0; i < 8; ++i) {
      int c = q * 8 + i;
      float v;
      if (c == 0)       v = node;
      else if (c <= 30) v = hrow[c - 1];
      else              v = 0.0f;
      au[i] = f2bf(v);
    }
    unsigned int off = (unsigned int)(r * 64 + q * 16) ^ (unsigned int)((r & 3) << 4);
    *reinterpret_cast<us8*>(ldsIn + off) = au;
  }
  __syncthreads();

  fx4 acc[8][4];

  // ======== layer 0: K=32 (one K-step), read ldsIn, barrier, store ldsAct ====
  {
    ACC_ZERO;
#pragma unroll
    for (int rt = 0; rt < 8; ++rt) {
      int m = rt * 16 + colb;
      unsigned int off = (unsigned int)(m * 64 + khalf * 16) ^ (unsigned int)((m & 3) << 4);
      bf8 a = *reinterpret_cast<const bf8*>(ldsIn + off);
      acc[rt][0] = __builtin_amdgcn_mfma_f32_16x16x32_bf16(wa0, a, acc[rt][0], 0, 0, 0);
      acc[rt][1] = __builtin_amdgcn_mfma_f32_16x16x32_bf16(wa1, a, acc[rt][1], 0, 0, 0);
      acc[rt][2] = __builtin_amdgcn_mfma_f32_16x16x32_bf16(wa2, a, acc[rt][2], 0, 0, 0);
      acc[rt][3] = __builtin_amdgcn_mfma_f32_16x16x32_bf16(wa3, a, acc[rt][3], 0, 0, 0);
    }
    // prefetch layer-1 kt0/kt1; loads straddle the barrier + store phase
    LOADW4(wa0, wa1, wa2, wa3, wb1p, 0);
    LOADW4(wb0, wb1, wb2, wb3, wb1p, 1);
    __syncthreads();                     // input region fully read by ALL waves
    ACT_STORE(b0);                       // now safe: overwrites overlay region
  }
  __syncthreads();

  // ======== layer 1 (in-place: read, barrier, store, barrier) ========
  ACC_ZERO;
  DENSE_PIPE(wb1p, wb2p);                // tail prefetches layer-2 kt0/kt1
  __syncthreads();
  ACT_STORE(b1);
  __syncthreads();

  // ======== layer 2 ========
  ACC_ZERO;
  DENSE_LAST(wb2p);
  __syncthreads();
  ACT_STORE(b2);
  __syncthreads();

  // ======== layer 3: 256 -> 1 via MFMA, wave wv handles rows wv*32..wv*32+31 ==
  {
    fx4 a30 = fx4{0.f, 0.f, 0.f, 0.f};
    fx4 a31 = fx4{0.f, 0.f, 0.f, 0.f};
    int m0 = wv * 32 + colb;
    int m1 = wv * 32 + 16 + colb;
#pragma unroll
    for (int kt = 0; kt < 8; ++kt) {
      bf8 w3f = *reinterpret_cast<const bf8*>(w3p + (kt * 64 + lane) * 8);
      bf8 a0 = *reinterpret_cast<const bf8*>(ldsAct + AOFF(m0, kt));
      bf8 a1 = *reinterpret_cast<const bf8*>(ldsAct + AOFF(m1, kt));
      a30 = __builtin_amdgcn_mfma_f32_16x16x32_bf16(w3f, a0, a30, 0, 0, 0);
      a31 = __builtin_amdgcn_mfma_f32_16x16x32_bf16(w3f, a1, a31, 0, 0, 0);
    }
    if (lane < 16) {
      float bias3 = b3[0];
      float y0 = a30[0] + bias3;
      float y1 = a31[0] + bias3;
      fbuf[R0 + wv * 32 + lane]      = (y0 > 0.f) ? (y0 + 1.f) : expf(y0);  // elu+1
      fbuf[R0 + wv * 32 + 16 + lane] = (y1 > 0.f) ? (y1 + 1.f) : expf(y1);
    }
  }
}

// ---------------- kernel 3: Clenshaw-Curtis reduction -> z, jac ----------------
__global__ void reduce_kernel(const float* __restrict__ x, const float* __restrict__ h,
                              const float* __restrict__ fbuf, float* __restrict__ out) {
  __shared__ float ccw[NS];
  int tid = threadIdx.x;
  if (tid < NS) {
    double acc = 0.0;
#pragma unroll
    for (int i = 0; i <= 20; i += 2) {
      double wi = (i == 0) ? 1.0 : 2.0 / (1.0 - (double)(i * i));
      acc += cos((double)(i * tid) * 3.141592653589793 / 20.0) * wi;
    }
    double edge = (tid == 0 || tid == 20) ? 0.5 : 1.0;
    ccw[tid] = (float)(acc * 0.1 * edge);          // * 2/nb_steps * edge
  }
  __syncthreads();
  int t = blockIdx.x * blockDim.x + tid;
  if (t >= NBD) return;
  const float* fb = fbuf + t * NS;
  float acc = 0.f;
#pragma unroll
  for (int i = 0; i < NS; ++i) acc += fb[i] * ccw[i];
  float z = acc * x[t] * 0.5f + h[t * NCOND];
  out[t] = z;                     // z_est + h[:,:,0]
  out[NBD + t] = fb[0];           // jac = f at node s=0 (steps[0]==1 -> input == [x,h])
}

// ---------------- launcher ----------------
extern "C" void kernel_launch(void* const* d_in, const int* in_sizes, int n_in,
                              void* d_out, int out_size, void* d_ws, size_t ws_size,
                              hipStream_t stream) {
  (void)in_sizes; (void)n_in; (void)out_size; (void)ws_size;
  const float* x  = (const float*)d_in[0];
  const float* h  = (const float*)d_in[1];
  const float* W0 = (const float*)d_in[2];
  const float* b0 = (const float*)d_in[3];
  const float* W1 = (const float*)d_in[4];
  const float* b1 = (const float*)d_in[5];
  const float* W2 = (const float*)d_in[6];
  const float* b2 = (const float*)d_in[7];
  const float* W3 = (const float*)d_in[8];
  const float* b3 = (const float*)d_in[9];

  unsigned short* wp = (unsigned short*)d_ws;
  float* fbuf = (float*)((char*)d_ws + WP_TOTAL * sizeof(unsigned short));
  float* out  = (float*)d_out;

  prep_pack<<<(WP_TOTAL / 8 + 255) / 256, 256, 0, stream>>>(W0, W1, W2, W3, wp);
  mlp_kernel<<<NBLOCKS, 256, 0, stream>>>(x, h, b0, b1, b2, b3, wp, fbuf);
  reduce_kernel<<<(NBD + 255) / 256, 256, 0, stream>>>(x, h, fbuf, out);
}

// Round 12
// 101.474 us; speedup vs baseline: 1.2847x; 1.2847x over previous
//
#include <hip/hip_runtime.h>
#include <math.h>

// ---------------- problem constants ----------------
#define NB        512
#define ND        32
#define NCOND     30
#define NS        21                  // NB_STEPS+1 quadrature nodes
#define NBD       (NB*ND)             // 16384
#define NROWS     (NBD*NS)            // 344064 MLP evaluations
#define MBLK      64                  // rows per block
#define NBLOCKS   (NROWS/MBLK)        // 5376

// packed-weight element counts (ushort)
#define W0P_ELEMS (1*16*64*8)         // 8192
#define W1P_ELEMS (8*16*64*8)         // 65536
#define W3P_ELEMS (8*64*8)            // 4096  (zero-padded W3 as A-fragments)
#define WP_TOTAL  (W0P_ELEMS + 2*W1P_ELEMS + W3P_ELEMS)  // 143360

typedef __bf16 bf8 __attribute__((ext_vector_type(8)));
typedef float  fx4 __attribute__((ext_vector_type(4)));
typedef unsigned short us8 __attribute__((ext_vector_type(8)));

__device__ __forceinline__ unsigned short f2bf(float f) {
  unsigned int u = __float_as_uint(f);
  u += 0x7FFFu + ((u >> 16) & 1u);        // round-to-nearest-even
  return (unsigned short)(u >> 16);
}

// ---------------- kernel 1: pack weights to bf16 MFMA fragment order ----------
__global__ void prep_pack(const float* __restrict__ W0,
                          const float* __restrict__ W1,
                          const float* __restrict__ W2,
                          const float* __restrict__ W3,
                          unsigned short* __restrict__ wp) {
  int t = blockIdx.x * blockDim.x + threadIdx.x;   // one thread = one 8-elem frag
  if (t >= WP_TOTAL / 8) return;
  int base = t * 8;
  us8 out;
  if (base >= W0P_ELEMS + 2 * W1P_ELEMS) {         // W3 region
    int rem  = base - (W0P_ELEMS + 2 * W1P_ELEMS);
    int lane = (rem >> 3) & 63;
    int ktl  = rem >> 9;
    int k0   = ktl * 32 + (lane >> 4) * 8;
#pragma unroll
    for (int i = 0; i < 8; ++i)
      out[i] = ((lane & 15) == 0) ? f2bf(W3[k0 + i]) : (unsigned short)0;
  } else {
    const float* W; int rem, K;
    if (base < W0P_ELEMS)                  { W = W0; rem = base;                 K = 31;  }
    else if (base < W0P_ELEMS + W1P_ELEMS) { W = W1; rem = base - W0P_ELEMS;     K = 256; }
    else                                   { W = W2; rem = base - W0P_ELEMS - W1P_ELEMS; K = 256; }
    int lane = (rem >> 3) & 63;
    int ct   = (rem >> 9) & 15;
    int ktl  =  rem >> 13;
    int j  = ct * 16 + (lane & 15);
    int k0 = ktl * 32 + (lane >> 4) * 8;
#pragma unroll
    for (int i = 0; i < 8; ++i) {
      int k = k0 + i;
      out[i] = (k < K) ? f2bf(W[k * 256 + j]) : (unsigned short)0;
    }
  }
  *reinterpret_cast<us8*>(wp + base) = out;
}

// ---------------- fused MLP kernel ----------------
// R10 geometry (4 waves/block, 64 rows, wave = 4 row-tiles x 4 col-tiles,
// ~110 VGPR, launch_bounds(256,2) -> cap 128) with two scheduling changes:
//  (a) PING-PONG act buffers (ldsA/ldsB, 32KB each): DENSE reads P, stores
//      write Q with NO barrier between -> fast waves stream cvt/ds_write
//      while slow waves still MFMA; ONE barrier per layer (after stores)
//      instead of two. R10's 39% MfmaUtil == DENSE(620cyc)/layer(1500cyc);
//      the fenced store phase was the stall.
//  (b) bias via accumulator INIT (C-in = bias broadcast per neuron) --
//      removes 64 VALU adds/thread/layer from the store phase.
// Input staging overlays ldsB[0:4KB]; L1's store to ldsB happens only after
// the L0 barrier, by which point input is fully consumed.

#define ACC_BIAS(BIAS)                                                           \
  {                                                                              \
    float4 bq0 = *reinterpret_cast<const float4*>((BIAS) + (cgrp * 4 + 0) * 16 + khalf * 4); \
    float4 bq1 = *reinterpret_cast<const float4*>((BIAS) + (cgrp * 4 + 1) * 16 + khalf * 4); \
    float4 bq2 = *reinterpret_cast<const float4*>((BIAS) + (cgrp * 4 + 2) * 16 + khalf * 4); \
    float4 bq3 = *reinterpret_cast<const float4*>((BIAS) + (cgrp * 4 + 3) * 16 + khalf * 4); \
    _Pragma("unroll")                                                            \
    for (int rt = 0; rt < 4; ++rt) {                                             \
      acc[rt][0] = fx4{bq0.x, bq0.y, bq0.z, bq0.w};                              \
      acc[rt][1] = fx4{bq1.x, bq1.y, bq1.z, bq1.w};                              \
      acc[rt][2] = fx4{bq2.x, bq2.y, bq2.z, bq2.w};                              \
      acc[rt][3] = fx4{bq3.x, bq3.y, bq3.z, bq3.w};                              \
    }                                                                            \
  }

#define LOADW4(S0,S1,S2,S3, WB, KT)                                              \
  S0 = *reinterpret_cast<const bf8*>((WB) + (((KT) * 16 + cgrp * 4 + 0) * 64 + lane) * 8); \
  S1 = *reinterpret_cast<const bf8*>((WB) + (((KT) * 16 + cgrp * 4 + 1) * 64 + lane) * 8); \
  S2 = *reinterpret_cast<const bf8*>((WB) + (((KT) * 16 + cgrp * 4 + 2) * 64 + lane) * 8); \
  S3 = *reinterpret_cast<const bf8*>((WB) + (((KT) * 16 + cgrp * 4 + 3) * 64 + lane) * 8);

#define AOFF(M, KT) (((unsigned)((M) * 512 + (KT) * 64 + khalf * 16)) ^ ((unsigned)(((M) & 15) << 4)))

#define KSTEP(SRC, W0_,W1_,W2_,W3_, KT)                                          \
  {                                                                              \
    bf8 a0 = *reinterpret_cast<const bf8*>((SRC) + AOFF( 0 + colb, KT));         \
    bf8 a1 = *reinterpret_cast<const bf8*>((SRC) + AOFF(16 + colb, KT));         \
    bf8 a2 = *reinterpret_cast<const bf8*>((SRC) + AOFF(32 + colb, KT));         \
    bf8 a3 = *reinterpret_cast<const bf8*>((SRC) + AOFF(48 + colb, KT));         \
    __builtin_amdgcn_s_setprio(1);                                               \
    acc[0][0] = __builtin_amdgcn_mfma_f32_16x16x32_bf16(W0_, a0, acc[0][0], 0, 0, 0); \
    acc[0][1] = __builtin_amdgcn_mfma_f32_16x16x32_bf16(W1_, a0, acc[0][1], 0, 0, 0); \
    acc[0][2] = __builtin_amdgcn_mfma_f32_16x16x32_bf16(W2_, a0, acc[0][2], 0, 0, 0); \
    acc[0][3] = __builtin_amdgcn_mfma_f32_16x16x32_bf16(W3_, a0, acc[0][3], 0, 0, 0); \
    acc[1][0] = __builtin_amdgcn_mfma_f32_16x16x32_bf16(W0_, a1, acc[1][0], 0, 0, 0); \
    acc[1][1] = __builtin_amdgcn_mfma_f32_16x16x32_bf16(W1_, a1, acc[1][1], 0, 0, 0); \
    acc[1][2] = __builtin_amdgcn_mfma_f32_16x16x32_bf16(W2_, a1, acc[1][2], 0, 0, 0); \
    acc[1][3] = __builtin_amdgcn_mfma_f32_16x16x32_bf16(W3_, a1, acc[1][3], 0, 0, 0); \
    acc[2][0] = __builtin_amdgcn_mfma_f32_16x16x32_bf16(W0_, a2, acc[2][0], 0, 0, 0); \
    acc[2][1] = __builtin_amdgcn_mfma_f32_16x16x32_bf16(W1_, a2, acc[2][1], 0, 0, 0); \
    acc[2][2] = __builtin_amdgcn_mfma_f32_16x16x32_bf16(W2_, a2, acc[2][2], 0, 0, 0); \
    acc[2][3] = __builtin_amdgcn_mfma_f32_16x16x32_bf16(W3_, a2, acc[2][3], 0, 0, 0); \
    acc[3][0] = __builtin_amdgcn_mfma_f32_16x16x32_bf16(W0_, a3, acc[3][0], 0, 0, 0); \
    acc[3][1] = __builtin_amdgcn_mfma_f32_16x16x32_bf16(W1_, a3, acc[3][1], 0, 0, 0); \
    acc[3][2] = __builtin_amdgcn_mfma_f32_16x16x32_bf16(W2_, a3, acc[3][2], 0, 0, 0); \
    acc[3][3] = __builtin_amdgcn_mfma_f32_16x16x32_bf16(W3_, a3, acc[3][3], 0, 0, 0); \
    __builtin_amdgcn_s_setprio(0);                                               \
  }

// K-steps 0..7, consuming alternating slots, prefetching kt+2 (then next layer)
#define DENSE_PIPE(SRC, WB, NWB)                                                 \
  KSTEP(SRC, wa0,wa1,wa2,wa3, 0) LOADW4(wa0,wa1,wa2,wa3, WB, 2)                  \
  KSTEP(SRC, wb0,wb1,wb2,wb3, 1) LOADW4(wb0,wb1,wb2,wb3, WB, 3)                  \
  KSTEP(SRC, wa0,wa1,wa2,wa3, 2) LOADW4(wa0,wa1,wa2,wa3, WB, 4)                  \
  KSTEP(SRC, wb0,wb1,wb2,wb3, 3) LOADW4(wb0,wb1,wb2,wb3, WB, 5)                  \
  KSTEP(SRC, wa0,wa1,wa2,wa3, 4) LOADW4(wa0,wa1,wa2,wa3, WB, 6)                  \
  KSTEP(SRC, wb0,wb1,wb2,wb3, 5) LOADW4(wb0,wb1,wb2,wb3, WB, 7)                  \
  KSTEP(SRC, wa0,wa1,wa2,wa3, 6) LOADW4(wa0,wa1,wa2,wa3, NWB, 0)                 \
  KSTEP(SRC, wb0,wb1,wb2,wb3, 7) LOADW4(wb0,wb1,wb2,wb3, NWB, 1)

#define DENSE_LAST(SRC, WB)                                                      \
  KSTEP(SRC, wa0,wa1,wa2,wa3, 0) LOADW4(wa0,wa1,wa2,wa3, WB, 2)                  \
  KSTEP(SRC, wb0,wb1,wb2,wb3, 1) LOADW4(wb0,wb1,wb2,wb3, WB, 3)                  \
  KSTEP(SRC, wa0,wa1,wa2,wa3, 2) LOADW4(wa0,wa1,wa2,wa3, WB, 4)                  \
  KSTEP(SRC, wb0,wb1,wb2,wb3, 3) LOADW4(wb0,wb1,wb2,wb3, WB, 5)                  \
  KSTEP(SRC, wa0,wa1,wa2,wa3, 4) LOADW4(wa0,wa1,wa2,wa3, WB, 6)                  \
  KSTEP(SRC, wb0,wb1,wb2,wb3, 5) LOADW4(wb0,wb1,wb2,wb3, WB, 7)                  \
  KSTEP(SRC, wa0,wa1,wa2,wa3, 6)                                                 \
  KSTEP(SRC, wb0,wb1,wb2,wb3, 7)

// ReLU + bf16-pack + ds_write_b64 store of acc into DST (bias already in acc)
#define ACT_STORE(DST)                                                           \
  {                                                                              \
    _Pragma("unroll")                                                            \
    for (int rt = 0; rt < 4; ++rt) {                                             \
      int m = rt * 16 + colb;                                                    \
      unsigned int sbase = (unsigned int)(m * 512);                              \
      unsigned int swz   = (unsigned int)((m & 15) << 4);                        \
      _Pragma("unroll")                                                          \
      for (int ct = 0; ct < 4; ++ct) {                                           \
        int n0 = (cgrp * 4 + ct) * 16 + khalf * 4;                               \
        float v0 = fmaxf(acc[rt][ct][0], 0.f);                                   \
        float v1 = fmaxf(acc[rt][ct][1], 0.f);                                   \
        float v2 = fmaxf(acc[rt][ct][2], 0.f);                                   \
        float v3 = fmaxf(acc[rt][ct][3], 0.f);                                   \
        unsigned int p0, p1;                                                     \
        asm("v_cvt_pk_bf16_f32 %0, %1, %2" : "=v"(p0) : "v"(v0), "v"(v1));       \
        asm("v_cvt_pk_bf16_f32 %0, %1, %2" : "=v"(p1) : "v"(v2), "v"(v3));       \
        uint2 pk; pk.x = p0; pk.y = p1;                                          \
        *reinterpret_cast<uint2*>((DST) + ((sbase + (unsigned int)(n0 * 2)) ^ swz)) = pk; \
      }                                                                          \
    }                                                                            \
  }

__global__ __launch_bounds__(256, 2)
void mlp_kernel(const float* __restrict__ x, const float* __restrict__ h,
                const float* __restrict__ b0, const float* __restrict__ b1,
                const float* __restrict__ b2, const float* __restrict__ b3,
                const unsigned short* __restrict__ wp,
                float* __restrict__ fbuf) {
  __shared__ __align__(16) unsigned char ldsA[64 * 512];     // 32 KiB
  __shared__ __align__(16) unsigned char ldsB[64 * 512];     // 32 KiB
  unsigned char* ldsIn = ldsB;         // layer-0 input overlays ldsB[0:4K]

  int tid  = threadIdx.x;
  int wv   = tid >> 6;
  int lane = tid & 63;
  int cgrp = wv;                 // 0..3 : 64-neuron group; wave owns all 64 rows
  int colb  = lane & 15;
  int khalf = lane >> 4;
  int R0 = blockIdx.x * MBLK;

  const unsigned short* wb1p = wp + W0P_ELEMS;
  const unsigned short* wb2p = wp + W0P_ELEMS + W1P_ELEMS;
  const unsigned short* w3p  = wp + W0P_ELEMS + 2 * W1P_ELEMS;

  bf8 wa0, wa1, wa2, wa3, wb0, wb1, wb2, wb3;
  // layer-0 weights (single K-step) into slot A, issued before input staging
  LOADW4(wa0, wa1, wa2, wa3, wp, 0);

  // ---- stage layer-0 input [64 rows][32 bf16] into ldsIn (= ldsB[0:4K]) ----
  {
    int r = tid >> 2;                   // 0..63
    int q = tid & 3;                    // 8-col chunk
    int gr = R0 + r;
    unsigned int bd = (unsigned int)gr / NS;
    int s = gr - (int)bd * NS;
    float xv = x[bd];
    float node = xv * (cosf((float)s * 0.15707963267948966f) + 1.0f) * 0.5f;
    const float* hrow = h + bd * NCOND;
    us8 au;
#pragma unroll
    for (int i = 0; i < 8; ++i) {
      int c = q * 8 + i;
      float v;
      if (c == 0)       v = node;
      else if (c <= 30) v = hrow[c - 1];
      else              v = 0.0f;
      au[i] = f2bf(v);
    }
    unsigned int off = (unsigned int)(r * 64 + q * 16) ^ (unsigned int)((r & 3) << 4);
    *reinterpret_cast<us8*>(ldsIn + off) = au;
  }
  __syncthreads();

  fx4 acc[4][4];

  // ======== layer 0: K=32, read ldsIn(B), store ldsA — no mid barrier ========
  {
    ACC_BIAS(b0);
#pragma unroll
    for (int rt = 0; rt < 4; ++rt) {
      int m = rt * 16 + colb;
      unsigned int off = (unsigned int)(m * 64 + khalf * 16) ^ (unsigned int)((m & 3) << 4);
      bf8 a = *reinterpret_cast<const bf8*>(ldsIn + off);
      acc[rt][0] = __builtin_amdgcn_mfma_f32_16x16x32_bf16(wa0, a, acc[rt][0], 0, 0, 0);
      acc[rt][1] = __builtin_amdgcn_mfma_f32_16x16x32_bf16(wa1, a, acc[rt][1], 0, 0, 0);
      acc[rt][2] = __builtin_amdgcn_mfma_f32_16x16x32_bf16(wa2, a, acc[rt][2], 0, 0, 0);
      acc[rt][3] = __builtin_amdgcn_mfma_f32_16x16x32_bf16(wa3, a, acc[rt][3], 0, 0, 0);
    }
    // prefetch layer-1 kt0/kt1; loads straddle the store + barrier
    LOADW4(wa0, wa1, wa2, wa3, wb1p, 0);
    LOADW4(wb0, wb1, wb2, wb3, wb1p, 1);
    ACT_STORE(ldsA);                    // different buffer: no barrier needed
  }
  __syncthreads();

  // ======== layer 1: read ldsA, store ldsB (one barrier after stores) ========
  ACC_BIAS(b1);
  DENSE_PIPE(ldsA, wb1p, wb2p);          // tail prefetches layer-2 kt0/kt1
  ACT_STORE(ldsB);
  __syncthreads();

  // ======== layer 2: read ldsB, store ldsA ========
  ACC_BIAS(b2);
  DENSE_LAST(ldsB, wb2p);
  ACT_STORE(ldsA);
  __syncthreads();

  // ======== layer 3: 256 -> 1 via MFMA, wave wv handles rows wv*16..wv*16+15 ==
  {
    fx4 a3 = fx4{0.f, 0.f, 0.f, 0.f};
    int m = wv * 16 + colb;
    unsigned int abase = (unsigned int)(m * 512 + khalf * 16);
    unsigned int aswz  = (unsigned int)((m & 15) << 4);
#pragma unroll
    for (int kt = 0; kt < 8; ++kt) {
      bf8 w3f = *reinterpret_cast<const bf8*>(w3p + (kt * 64 + lane) * 8);
      bf8 a = *reinterpret_cast<const bf8*>(ldsA + ((abase + (unsigned)(kt * 64)) ^ aswz));
      a3 = __builtin_amdgcn_mfma_f32_16x16x32_bf16(w3f, a, a3, 0, 0, 0);
    }
    if (lane < 16) {
      float y = a3[0] + b3[0];
      float f = (y > 0.f) ? (y + 1.f) : expf(y);   // elu(y)+1
      fbuf[R0 + wv * 16 + lane] = f;
    }
  }
}

// ---------------- kernel 3: Clenshaw-Curtis reduction -> z, jac ----------------
__global__ void reduce_kernel(const float* __restrict__ x, const float* __restrict__ h,
                              const float* __restrict__ fbuf, float* __restrict__ out) {
  __shared__ float ccw[NS];
  int tid = threadIdx.x;
  if (tid < NS) {
    double acc = 0.0;
#pragma unroll
    for (int i = 0; i <= 20; i += 2) {
      double wi = (i == 0) ? 1.0 : 2.0 / (1.0 - (double)(i * i));
      acc += cos((double)(i * tid) * 3.141592653589793 / 20.0) * wi;
    }
    double edge = (tid == 0 || tid == 20) ? 0.5 : 1.0;
    ccw[tid] = (float)(acc * 0.1 * edge);          // * 2/nb_steps * edge
  }
  __syncthreads();
  int t = blockIdx.x * blockDim.x + tid;
  if (t >= NBD) return;
  const float* fb = fbuf + t * NS;
  float acc = 0.f;
#pragma unroll
  for (int i = 0; i < NS; ++i) acc += fb[i] * ccw[i];
  float z = acc * x[t] * 0.5f + h[t * NCOND];
  out[t] = z;                     // z_est + h[:,:,0]
  out[NBD + t] = fb[0];           // jac = f at node s=0 (steps[0]==1 -> input == [x,h])
}

// ---------------- launcher ----------------
extern "C" void kernel_launch(void* const* d_in, const int* in_sizes, int n_in,
                              void* d_out, int out_size, void* d_ws, size_t ws_size,
                              hipStream_t stream) {
  (void)in_sizes; (void)n_in; (void)out_size; (void)ws_size;
  const float* x  = (const float*)d_in[0];
  const float* h  = (const float*)d_in[1];
  const float* W0 = (const float*)d_in[2];
  const float* b0 = (const float*)d_in[3];
  const float* W1 = (const float*)d_in[4];
  const float* b1 = (const float*)d_in[5];
  const float* W2 = (const float*)d_in[6];
  const float* b2 = (const float*)d_in[7];
  const float* W3 = (const float*)d_in[8];
  const float* b3 = (const float*)d_in[9];

  unsigned short* wp = (unsigned short*)d_ws;
  float* fbuf = (float*)((char*)d_ws + WP_TOTAL * sizeof(unsigned short));
  float* out  = (float*)d_out;

  prep_pack<<<(WP_TOTAL / 8 + 255) / 256, 256, 0, stream>>>(W0, W1, W2, W3, wp);
  mlp_kernel<<<NBLOCKS, 256, 0, stream>>>(x, h, b0, b1, b2, b3, wp, fbuf);
  reduce_kernel<<<(NBD + 255) / 256, 256, 0, stream>>>(x, h, fbuf, out);
}